// Round 5
// baseline (119.894 us; speedup 1.0000x reference)
//
#include <hip/hip_runtime.h>
#include <cstdint>

// ECT loss, exact elementwise formulation (absmax 0.0 preserved).
// A[bc][r][d] = sum_p dw[b,p,c] * sigmoid(8*(lin_r - <x_p, v_d>)), c in {0,1};
// c2 = -(c0+c1); loss = mean over 12288.
//
// R5: force fp32 packing in the inner loop.
//  * R4's f32x2 intrinsic code scalarized (VALU-busy time unchanged at ~33us;
//    the z2.yx swizzle poisoned VOP3P selection). Fix: RELABEL instead of
//    swizzle — ssw = z2*rr = (sig_{2h+1}, sig_{2h}); accumulate swapped and
//    swap .x/.y at the store (zero instructions).
//  * inline asm v_pk_fma_f32 / v_pk_mul_f32 (pair operands, no modifiers)
//    guarantees packed issue: ~52 scalar -> ~32 packed + ~10 movs per voxel.
// Structure unchanged from R4: 1024 blocks x 108 voxels store path + red;
// fallback chain 1024-store -> 512-store -> atomic by ws_size.

typedef float f32x2 __attribute__((ext_vector_type(2)));

#define P_TOT 110592
#define NREP 4  // atomic fallback only

// packed fp32 ops — guaranteed VOP3P issue (pair operands print as v[n:n+1])
#define PK_FMA(d_, a_, b_, c_) \
  asm("v_pk_fma_f32 %0, %1, %2, %3" : "=v"(d_) : "v"(a_), "v"(b_), "v"(c_))
#define PK_MUL(d_, a_, b_) \
  asm("v_pk_mul_f32 %0, %1, %2" : "=v"(d_) : "v"(a_), "v"(b_))
#define PK_FMA_ACC(acc_, a_, b_) \
  asm("v_pk_fma_f32 %0, %1, %2, %0" : "+v"(acc_) : "v"(a_), "v"(b_))

__device__ __forceinline__ uint32_t rotl32(uint32_t x, int d) {
  return (x << d) | (x >> (32 - d));
}

// threefry2x32, key = (0,17) — bit-exact vs jax (verified)
__device__ __forceinline__ void threefry_0_17(uint32_t x0, uint32_t x1,
                                              uint32_t& o0, uint32_t& o1) {
  const uint32_t ks0 = 0u, ks1 = 17u, ks2 = 0x1BD11BDAu ^ 0u ^ 17u;
  x0 += ks0; x1 += ks1;
#define R4(a,b,c,dd) \
  x0 += x1; x1 = rotl32(x1,(a)); x1 ^= x0; \
  x0 += x1; x1 = rotl32(x1,(b)); x1 ^= x0; \
  x0 += x1; x1 = rotl32(x1,(c)); x1 ^= x0; \
  x0 += x1; x1 = rotl32(x1,(dd)); x1 ^= x0;
  R4(13,15,26,6)   x0 += ks1; x1 += ks2 + 1u;
  R4(17,29,16,24)  x0 += ks2; x1 += ks0 + 2u;
  R4(13,15,26,6)   x0 += ks0; x1 += ks1 + 3u;
  R4(17,29,16,24)  x0 += ks1; x1 += ks2 + 4u;
  R4(13,15,26,6)   x0 += ks2; x1 += ks0 + 5u;
#undef R4
  o0 = x0; o1 = x1;
}

// XLA ErfInv32 — bit-exact vs jax (verified)
__device__ __forceinline__ float erfinv_f32(float x) {
  float w = -log1pf(-x * x);
  float p;
  if (w < 5.0f) {
    w = w - 2.5f;
    p = 2.81022636e-08f;
    p = fmaf(p, w, 3.43273939e-07f);
    p = fmaf(p, w, -3.5233877e-06f);
    p = fmaf(p, w, -4.39150654e-06f);
    p = fmaf(p, w, 0.00021858087f);
    p = fmaf(p, w, -0.00125372503f);
    p = fmaf(p, w, -0.00417768164f);
    p = fmaf(p, w, 0.246640727f);
    p = fmaf(p, w, 1.50140941f);
  } else {
    w = sqrtf(w) - 3.0f;
    p = -0.000200214257f;
    p = fmaf(p, w, 0.000100950558f);
    p = fmaf(p, w, 0.00134934322f);
    p = fmaf(p, w, 0.000337081863f);
    p = fmaf(p, w, 0.00573950773f);
    p = fmaf(p, w, -0.0076224613f);
    p = fmaf(p, w, 0.00943887047f);
    p = fmaf(p, w, 1.00167406f);
    p = fmaf(p, w, 2.83297682f);
  }
  return p * x;
}

// ---------- shared compute ----------
// accp[h][bc] = ( sum for r=rg*8+2h+1 , sum for r=rg*8+2h )   [RELABELED]
template <int VOXN>
__device__ __forceinline__ void ect_block_compute(
    const float* __restrict__ pred, const int* __restrict__ tgt,
    float* dirs, float4* voxdw, float4* voxc,
    int t, int bx, f32x2 accp[4][4]) {
  const int d = t & 31;
  const int rg = t >> 5;
  const int cbase = bx * VOXN;

  if (t < 96) {
    uint32_t o0, o1;
    threefry_0_17(0u, (uint32_t)t, o0, o1);
    uint32_t bits = o0 ^ o1;
    float u = __uint_as_float((bits >> 9) | 0x3F800000u) - 1.0f;
    const float lo = -0.99999994f;
    float v = fmaf(u, 2.0f, lo);
    v = fmaxf(v, lo);
    dirs[t] = 1.41421356237f * erfinv_f32(v);
  }
  __syncthreads();
  if (t < 32) {
    float a = dirs[t], b = dirs[32 + t], c = dirs[64 + t];
    float n = fmaxf(sqrtf(a * a + b * b + c * c), 1e-12f);
    dirs[t] = a / n; dirs[32 + t] = b / n; dirs[64 + t] = c / n;
  }
  if (t < VOXN) {
    int p = cbase + t;
    int ix = p / 2304; int rem = p - ix * 2304;
    int iy = rem / 48; int iz = rem - iy * 48;
    const float delta = 2.0f / 47.0f;
    voxc[t] = float4{(float)ix * delta - 1.0f, (float)iy * delta - 1.0f,
                     (float)iz * delta - 1.0f, 0.0f};
    float w[4];
#pragma unroll
    for (int b = 0; b < 2; b++) {
      const float* pb = pred + b * (3 * P_TOT) + p;
      float x0 = pb[0], x1 = pb[P_TOT], x2 = pb[2 * P_TOT];
      float m = fmaxf(x0, fmaxf(x1, x2));
      float e0 = __expf(x0 - m), e1 = __expf(x1 - m), e2 = __expf(x2 - m);
      float inv = 1.0f / (e0 + e1 + e2);
      int tg = tgt[b * P_TOT + p];
      w[b * 2 + 0] = e0 * inv - ((tg == 0) ? 1.0f : 0.0f);
      w[b * 2 + 1] = e1 * inv - ((tg == 1) ? 1.0f : 0.0f);
    }
    voxdw[t] = float4{w[0], w[1], w[2], w[3]};
  }
  __syncthreads();

  const float dir0 = dirs[d], dir1 = dirs[32 + d], dir2 = dirs[64 + d];
  const float radius = 1.1f * 1.7320508075688772f;
  const float step = (2.0f * radius) / 63.0f;
  f32x2 K2[4];
#pragma unroll
  for (int h = 0; h < 4; h++) {
    float l0 = fmaf((float)(rg * 8 + 2 * h), step, -radius);
    float l1 = fmaf((float)(rg * 8 + 2 * h + 1), step, -radius);
    K2[h] = f32x2{__expf(-8.0f * l0), __expf(-8.0f * l1)};
  }
  const f32x2 one2 = {1.0f, 1.0f};
#pragma unroll
  for (int h = 0; h < 4; h++)
#pragma unroll
    for (int bc = 0; bc < 4; bc++) accp[h][bc] = f32x2{0.0f, 0.0f};

#pragma unroll 4
  for (int v = 0; v < VOXN; v++) {
    float4 c = voxc[v];
    float4 w = voxdw[v];
    float nh = fmaf(c.z, dir2, fmaf(c.y, dir1, c.x * dir0));
    float E = __expf(8.0f * nh);              // <= e^13.9, no overflow
    f32x2 E2 = {E, E};
    f32x2 wx = {w.x, w.x}, wy = {w.y, w.y}, wz = {w.z, w.z}, w3 = {w.w, w.w};
#pragma unroll
    for (int h = 0; h < 4; h++) {
      f32x2 z2;                                // (z_{2h}, z_{2h+1}), 1..4.4e12
      PK_FMA(z2, E2, K2[h], one2);
      // paired reciprocal: product <= 2e25, no overflow
      float pz = z2.x * z2.y;
      float rr = __builtin_amdgcn_rcpf(pz);
      f32x2 rr2 = {rr, rr};
      f32x2 ssw;                               // (sig_{2h+1}, sig_{2h}) — swapped
      PK_MUL(ssw, z2, rr2);                    //   on purpose; fixed at store
      PK_FMA_ACC(accp[h][0], wx, ssw);
      PK_FMA_ACC(accp[h][1], wy, ssw);
      PK_FMA_ACC(accp[h][2], wz, ssw);
      PK_FMA_ACC(accp[h][3], w3, ssw);
    }
  }
}

// ---------- store path ----------
template <int VOXN>
__global__ __launch_bounds__(256, 2) void ect_main_st(
    const float* __restrict__ pred, const int* __restrict__ tgt,
    float* __restrict__ part) {
  __shared__ float dirs[96];
  __shared__ float4 voxdw[VOXN];
  __shared__ float4 voxc[VOXN];
  const int t = threadIdx.x;
  const int bx = blockIdx.x;
  const int d = t & 31;
  const int rg = t >> 5;
  f32x2 accp[4][4];
  ect_block_compute<VOXN>(pred, tgt, dirs, voxdw, voxc, t, bx, accp);

  // relabel fix: .y holds r=2h, .x holds r=2h+1
  float4* prt = (float4*)part + (size_t)bx * 2048;
#pragma unroll
  for (int h = 0; h < 4; h++) {
    prt[(rg * 8 + 2 * h) * 32 + d] =
        float4{accp[h][0].y, accp[h][1].y, accp[h][2].y, accp[h][3].y};
    prt[(rg * 8 + 2 * h + 1) * 32 + d] =
        float4{accp[h][0].x, accp[h][1].x, accp[h][2].x, accp[h][3].x};
  }
}

__global__ __launch_bounds__(256) void ect_red(
    const float* __restrict__ part, float* __restrict__ gacc2,
    float* __restrict__ out, int ngrid) {
  __shared__ float redf[4];
  __shared__ int islast;
  const int t = threadIdx.x;
  const int rc = blockIdx.x >> 3;       // slice chunk (32 slices each)
  const int cc = blockIdx.x & 7;        // column chunk (256 float4)
  const int c4 = cc * 256 + t;          // float4 column in [0, 2048)
  const float4* p4 = (const float4*)part;

  float a0 = 0.f, a1 = 0.f, a2 = 0.f, a3 = 0.f;
#pragma unroll 8
  for (int r = rc * 32; r < rc * 32 + 32; ++r) {
    float4 v = p4[(size_t)r * 2048 + c4];   // 1KB-coalesced per wave per r
    a0 += v.x; a1 += v.y; a2 += v.z; a3 += v.w;
  }
  atomicAdd(&gacc2[c4 * 4 + 0], a0);
  atomicAdd(&gacc2[c4 * 4 + 1], a1);
  atomicAdd(&gacc2[c4 * 4 + 2], a2);
  atomicAdd(&gacc2[c4 * 4 + 3], a3);

  __syncthreads();                       // drains vmcnt(0) per wave
  unsigned int* cnt = (unsigned int*)(gacc2 + 8192);
  if (t == 0) {
    unsigned int old = __hip_atomic_fetch_add(cnt, 1u, __ATOMIC_RELAXED,
                                              __HIP_MEMORY_SCOPE_AGENT);
    islast = (old == (unsigned int)(ngrid - 1)) ? 1 : 0;
  }
  __syncthreads();
  if (islast) {
    float s = 0.0f;
    for (int i = t; i < 2048; i += 256) {  // i = r*32 + d
      const unsigned long long* p64 =
          (const unsigned long long*)(gacc2 + i * 4);
      unsigned long long q0 = __hip_atomic_load(p64, __ATOMIC_RELAXED,
                                                __HIP_MEMORY_SCOPE_AGENT);
      unsigned long long q1 = __hip_atomic_load(p64 + 1, __ATOMIC_RELAXED,
                                                __HIP_MEMORY_SCOPE_AGENT);
      float b0 = __uint_as_float((unsigned int)q0);
      float b1 = __uint_as_float((unsigned int)(q0 >> 32));
      float b2 = __uint_as_float((unsigned int)q1);
      float b3 = __uint_as_float((unsigned int)(q1 >> 32));
      s += b0 * b0 + b1 * b1 + (b0 + b1) * (b0 + b1)
         + b2 * b2 + b3 * b3 + (b2 + b3) * (b2 + b3);
    }
#pragma unroll
    for (int off = 32; off > 0; off >>= 1) s += __shfl_down(s, off, 64);
    if ((t & 63) == 0) redf[t >> 6] = s;
    __syncthreads();
    if (t == 0)
      out[0] = (redf[0] + redf[1] + redf[2] + redf[3]) * (1.0f / 12288.0f);
  }
}

// ---------- atomic fallback (proven structure) ----------
__global__ __launch_bounds__(256, 2) void ect_main_at(
    const float* __restrict__ pred, const int* __restrict__ tgt,
    float* __restrict__ gacc) {
  __shared__ float dirs[96];
  __shared__ float4 voxdw[216];
  __shared__ float4 voxc[216];
  const int t = threadIdx.x;
  const int bx = blockIdx.x;
  const int d = t & 31;
  const int rg = t >> 5;
  f32x2 accp[4][4];
  ect_block_compute<216>(pred, tgt, dirs, voxdw, voxc, t, bx, accp);

  // relabel fix: .y holds r=2h, .x holds r=2h+1
  float* grep = gacc + (size_t)(bx & (NREP - 1)) * 8192;
#pragma unroll
  for (int h = 0; h < 4; h++) {
    int b0 = ((rg * 8 + 2 * h) * 32 + d) * 4;
    int b1 = ((rg * 8 + 2 * h + 1) * 32 + d) * 4;
    atomicAdd(&grep[b0 + 0], accp[h][0].y);
    atomicAdd(&grep[b0 + 1], accp[h][1].y);
    atomicAdd(&grep[b0 + 2], accp[h][2].y);
    atomicAdd(&grep[b0 + 3], accp[h][3].y);
    atomicAdd(&grep[b1 + 0], accp[h][0].x);
    atomicAdd(&grep[b1 + 1], accp[h][1].x);
    atomicAdd(&grep[b1 + 2], accp[h][2].x);
    atomicAdd(&grep[b1 + 3], accp[h][3].x);
  }
}

__global__ __launch_bounds__(256) void ect_fin(
    const float* __restrict__ gacc, float* __restrict__ out) {
  __shared__ float red[4];
  int t = threadIdx.x;
  float s = 0.0f;
  for (int i = t; i < 2048; i += 256) {
    float a0 = 0.f, a1 = 0.f, a2 = 0.f, a3 = 0.f;
#pragma unroll
    for (int rep = 0; rep < NREP; rep++) {
      const float4 g = *(const float4*)(gacc + (size_t)rep * 8192 + i * 4);
      a0 += g.x; a1 += g.y; a2 += g.z; a3 += g.w;
    }
    s += a0 * a0 + a1 * a1 + (a0 + a1) * (a0 + a1)
       + a2 * a2 + a3 * a3 + (a2 + a3) * (a2 + a3);
  }
#pragma unroll
  for (int off = 32; off > 0; off >>= 1) s += __shfl_down(s, off, 64);
  if ((t & 63) == 0) red[t >> 6] = s;
  __syncthreads();
  if (t == 0) out[0] = (red[0] + red[1] + red[2] + red[3]) * (1.0f / 12288.0f);
}

extern "C" void kernel_launch(void* const* d_in, const int* in_sizes, int n_in,
                              void* d_out, int out_size, void* d_ws, size_t ws_size,
                              hipStream_t stream) {
  const float* pred = (const float*)d_in[0];
  const int* tgt = (const int*)d_in[1];
  float* ws = (float*)d_ws;
  float* out = (float*)d_out;

  const size_t need1024 = ((size_t)1024 * 8192 + 8192 + 64) * sizeof(float);
  const size_t need512 = ((size_t)512 * 8192 + 8192 + 64) * sizeof(float);

  if (ws_size >= need1024) {
    // 1024 blocks x 108 voxels
    float* part = ws;                                   // [1024][8192]
    float* gacc2 = ws + (size_t)1024 * 8192;
    hipMemsetAsync(gacc2, 0, (8192 + 64) * sizeof(float), stream);
    hipLaunchKernelGGL(ect_main_st<108>, dim3(1024), dim3(256), 0, stream,
                       pred, tgt, part);
    hipLaunchKernelGGL(ect_red, dim3(256), dim3(256), 0, stream,
                       part, gacc2, out, 256);
  } else if (ws_size >= need512) {
    float* part = ws;                                   // [512][8192]
    float* gacc2 = ws + (size_t)512 * 8192;
    hipMemsetAsync(gacc2, 0, (8192 + 64) * sizeof(float), stream);
    hipLaunchKernelGGL(ect_main_st<216>, dim3(512), dim3(256), 0, stream,
                       pred, tgt, part);
    hipLaunchKernelGGL(ect_red, dim3(128), dim3(256), 0, stream,
                       part, gacc2, out, 128);
  } else {
    float* gacc = ws;                                   // 4*8192 floats
    hipMemsetAsync(gacc, 0, (size_t)NREP * 8192 * sizeof(float), stream);
    hipLaunchKernelGGL(ect_main_at, dim3(512), dim3(256), 0, stream,
                       pred, tgt, gacc);
    hipLaunchKernelGGL(ect_fin, dim3(1), dim3(256), 0, stream, gacc, out);
  }
}

// Round 6
// 119.062 us; speedup vs baseline: 1.0070x; 1.0070x over previous
//
#include <hip/hip_runtime.h>
#include <cstdint>

// ECT loss, exact elementwise formulation (absmax 0.0 preserved).
// A[bc][r][d] = sum_p dw[b,p,c] * sigmoid(8*(lin_r - <x_p, v_d>)), c in {0,1};
// c2 = -(c0+c1); loss = mean over 12288.
//
// R6: move per-voxel data (coords + dw) off the LDS pipe onto the scalar path.
//  * R5 lesson: pk fp32 is NOT 2x on CDNA4 (157 TF peak already = scalar fma
//    rate); reverted to the proven scalar inner loop (R3/R4 codegen).
//  * ect_pre precomputes voxc[P] and voxw[P] (float4 each) to global ws once.
//  * main loop reads them via uniform-address loads (cbase+v is uniform ->
//    s_load_dwordx4 / broadcast VMEM; zero LDS traffic, zero lgkmcnt-on-LDS
//    in the loop; SGPR operands feed v_fma directly). LDS shrinks to dirs[96].
//  * store path + red unchanged from R4 (proven).
// Fallback chain by ws_size: 1024-smem -> 512-smem -> atomic (R0 path).

#define P_TOT 110592
#define NREP 4  // atomic fallback only

__device__ __forceinline__ uint32_t rotl32(uint32_t x, int d) {
  return (x << d) | (x >> (32 - d));
}

// threefry2x32, key = (0,17) — bit-exact vs jax (verified)
__device__ __forceinline__ void threefry_0_17(uint32_t x0, uint32_t x1,
                                              uint32_t& o0, uint32_t& o1) {
  const uint32_t ks0 = 0u, ks1 = 17u, ks2 = 0x1BD11BDAu ^ 0u ^ 17u;
  x0 += ks0; x1 += ks1;
#define R4(a,b,c,dd) \
  x0 += x1; x1 = rotl32(x1,(a)); x1 ^= x0; \
  x0 += x1; x1 = rotl32(x1,(b)); x1 ^= x0; \
  x0 += x1; x1 = rotl32(x1,(c)); x1 ^= x0; \
  x0 += x1; x1 = rotl32(x1,(dd)); x1 ^= x0;
  R4(13,15,26,6)   x0 += ks1; x1 += ks2 + 1u;
  R4(17,29,16,24)  x0 += ks2; x1 += ks0 + 2u;
  R4(13,15,26,6)   x0 += ks0; x1 += ks1 + 3u;
  R4(17,29,16,24)  x0 += ks1; x1 += ks2 + 4u;
  R4(13,15,26,6)   x0 += ks2; x1 += ks0 + 5u;
#undef R4
  o0 = x0; o1 = x1;
}

// XLA ErfInv32 — bit-exact vs jax (verified)
__device__ __forceinline__ float erfinv_f32(float x) {
  float w = -log1pf(-x * x);
  float p;
  if (w < 5.0f) {
    w = w - 2.5f;
    p = 2.81022636e-08f;
    p = fmaf(p, w, 3.43273939e-07f);
    p = fmaf(p, w, -3.5233877e-06f);
    p = fmaf(p, w, -4.39150654e-06f);
    p = fmaf(p, w, 0.00021858087f);
    p = fmaf(p, w, -0.00125372503f);
    p = fmaf(p, w, -0.00417768164f);
    p = fmaf(p, w, 0.246640727f);
    p = fmaf(p, w, 1.50140941f);
  } else {
    w = sqrtf(w) - 3.0f;
    p = -0.000200214257f;
    p = fmaf(p, w, 0.000100950558f);
    p = fmaf(p, w, 0.00134934322f);
    p = fmaf(p, w, 0.000337081863f);
    p = fmaf(p, w, 0.00573950773f);
    p = fmaf(p, w, -0.0076224613f);
    p = fmaf(p, w, 0.00943887047f);
    p = fmaf(p, w, 1.00167406f);
    p = fmaf(p, w, 2.83297682f);
  }
  return p * x;
}

// ---------- pre: per-voxel coords + dw (softmax - onehot), once ----------
__global__ __launch_bounds__(256) void ect_pre(
    const float* __restrict__ pred, const int* __restrict__ tgt,
    float4* __restrict__ voxc, float4* __restrict__ voxw) {
  const int p = blockIdx.x * 256 + threadIdx.x;   // grid 432 -> exactly P_TOT
  int ix = p / 2304; int rem = p - ix * 2304;
  int iy = rem / 48; int iz = rem - iy * 48;
  const float delta = 2.0f / 47.0f;
  voxc[p] = float4{(float)ix * delta - 1.0f, (float)iy * delta - 1.0f,
                   (float)iz * delta - 1.0f, 0.0f};
  float w[4];
#pragma unroll
  for (int b = 0; b < 2; b++) {
    const float* pb = pred + b * (3 * P_TOT) + p;
    float x0 = pb[0], x1 = pb[P_TOT], x2 = pb[2 * P_TOT];
    float m = fmaxf(x0, fmaxf(x1, x2));
    float e0 = __expf(x0 - m), e1 = __expf(x1 - m), e2 = __expf(x2 - m);
    float inv = 1.0f / (e0 + e1 + e2);
    int tg = tgt[b * P_TOT + p];
    w[b * 2 + 0] = e0 * inv - ((tg == 0) ? 1.0f : 0.0f);
    w[b * 2 + 1] = e1 * inv - ((tg == 1) ? 1.0f : 0.0f);
  }
  voxw[p] = float4{w[0], w[1], w[2], w[3]};
}

// ---------- main: scalar-path voxel reads, zero in-loop LDS ----------
template <int VOXN>
__global__ __launch_bounds__(256, 2) void ect_main_sm(
    const float4* __restrict__ voxc, const float4* __restrict__ voxw,
    float* __restrict__ part) {
  __shared__ float dirs[96];        // only LDS left: [3][32] unit directions

  const int t = threadIdx.x;
  const int bx = blockIdx.x;
  const int d = t & 31;
  const int rg = t >> 5;
  const int cbase = bx * VOXN;      // uniform

  if (t < 96) {
    uint32_t o0, o1;
    threefry_0_17(0u, (uint32_t)t, o0, o1);
    uint32_t bits = o0 ^ o1;
    float u = __uint_as_float((bits >> 9) | 0x3F800000u) - 1.0f;
    const float lo = -0.99999994f;
    float v = fmaf(u, 2.0f, lo);
    v = fmaxf(v, lo);
    dirs[t] = 1.41421356237f * erfinv_f32(v);
  }
  __syncthreads();
  if (t < 32) {
    float a = dirs[t], b = dirs[32 + t], c = dirs[64 + t];
    float n = fmaxf(sqrtf(a * a + b * b + c * c), 1e-12f);
    dirs[t] = a / n; dirs[32 + t] = b / n; dirs[64 + t] = c / n;
  }
  __syncthreads();                  // normalize must complete before reads

  const float dir0 = dirs[d], dir1 = dirs[32 + d], dir2 = dirs[64 + d];
  const float radius = 1.1f * 1.7320508075688772f;
  const float step = (2.0f * radius) / 63.0f;
  float K[8];
#pragma unroll
  for (int j = 0; j < 8; j++) {
    float lin = fmaf((float)(rg * 8 + j), step, -radius);
    K[j] = __expf(-8.0f * lin);
  }

  float acc[8][4];
#pragma unroll
  for (int j = 0; j < 8; j++)
#pragma unroll
    for (int bc = 0; bc < 4; bc++) acc[j][bc] = 0.0f;

  // main loop: voxel data via uniform-address loads (scalar path), no LDS
#pragma unroll 4
  for (int v = 0; v < VOXN; v++) {
    const float4 c = voxc[cbase + v];   // uniform address -> s_load_dwordx4
    const float4 w = voxw[cbase + v];
    float nh = fmaf(c.z, dir2, fmaf(c.y, dir1, c.x * dir0));
    float E = __expf(8.0f * nh);              // <= e^13.9, no overflow
    float z[8];
#pragma unroll
    for (int j = 0; j < 8; j++) z[j] = fmaf(E, K[j], 1.0f);  // 1..4.4e12
#pragma unroll
    for (int h = 0; h < 4; h++) {
      // paired reciprocal: product <= 2e25, no overflow
      float pz = z[2 * h] * z[2 * h + 1];
      float rr = __builtin_amdgcn_rcpf(pz);
      float s0 = z[2 * h + 1] * rr;           // sigmoid for r = rg*8+2h
      float s1 = z[2 * h] * rr;               // sigmoid for r = rg*8+2h+1
      acc[2 * h][0] = fmaf(w.x, s0, acc[2 * h][0]);
      acc[2 * h][1] = fmaf(w.y, s0, acc[2 * h][1]);
      acc[2 * h][2] = fmaf(w.z, s0, acc[2 * h][2]);
      acc[2 * h][3] = fmaf(w.w, s0, acc[2 * h][3]);
      acc[2 * h + 1][0] = fmaf(w.x, s1, acc[2 * h + 1][0]);
      acc[2 * h + 1][1] = fmaf(w.y, s1, acc[2 * h + 1][1]);
      acc[2 * h + 1][2] = fmaf(w.z, s1, acc[2 * h + 1][2]);
      acc[2 * h + 1][3] = fmaf(w.w, s1, acc[2 * h + 1][3]);
    }
  }

  // epilogue: pure coalesced stores: part[bx][(r*32+d)*4 + bc]
  float4* prt = (float4*)part + (size_t)bx * 2048;
#pragma unroll
  for (int j = 0; j < 8; j++) {
    prt[(rg * 8 + j) * 32 + d] =
        float4{acc[j][0], acc[j][1], acc[j][2], acc[j][3]};
  }
}

__global__ __launch_bounds__(256) void ect_red(
    const float* __restrict__ part, float* __restrict__ gacc2,
    float* __restrict__ out, int ngrid) {
  __shared__ float redf[4];
  __shared__ int islast;
  const int t = threadIdx.x;
  const int rc = blockIdx.x >> 3;       // slice chunk (32 slices each)
  const int cc = blockIdx.x & 7;        // column chunk (256 float4)
  const int c4 = cc * 256 + t;          // float4 column in [0, 2048)
  const float4* p4 = (const float4*)part;

  float a0 = 0.f, a1 = 0.f, a2 = 0.f, a3 = 0.f;
#pragma unroll 8
  for (int r = rc * 32; r < rc * 32 + 32; ++r) {
    float4 v = p4[(size_t)r * 2048 + c4];   // 1KB-coalesced per wave per r
    a0 += v.x; a1 += v.y; a2 += v.z; a3 += v.w;
  }
  atomicAdd(&gacc2[c4 * 4 + 0], a0);
  atomicAdd(&gacc2[c4 * 4 + 1], a1);
  atomicAdd(&gacc2[c4 * 4 + 2], a2);
  atomicAdd(&gacc2[c4 * 4 + 3], a3);

  __syncthreads();                       // drains vmcnt(0) per wave
  unsigned int* cnt = (unsigned int*)(gacc2 + 8192);
  if (t == 0) {
    unsigned int old = __hip_atomic_fetch_add(cnt, 1u, __ATOMIC_RELAXED,
                                              __HIP_MEMORY_SCOPE_AGENT);
    islast = (old == (unsigned int)(ngrid - 1)) ? 1 : 0;
  }
  __syncthreads();
  if (islast) {
    float s = 0.0f;
    for (int i = t; i < 2048; i += 256) {  // i = r*32 + d
      const unsigned long long* p64 =
          (const unsigned long long*)(gacc2 + i * 4);
      unsigned long long q0 = __hip_atomic_load(p64, __ATOMIC_RELAXED,
                                                __HIP_MEMORY_SCOPE_AGENT);
      unsigned long long q1 = __hip_atomic_load(p64 + 1, __ATOMIC_RELAXED,
                                                __HIP_MEMORY_SCOPE_AGENT);
      float b0 = __uint_as_float((unsigned int)q0);
      float b1 = __uint_as_float((unsigned int)(q0 >> 32));
      float b2 = __uint_as_float((unsigned int)q1);
      float b3 = __uint_as_float((unsigned int)(q1 >> 32));
      s += b0 * b0 + b1 * b1 + (b0 + b1) * (b0 + b1)
         + b2 * b2 + b3 * b3 + (b2 + b3) * (b2 + b3);
    }
#pragma unroll
    for (int off = 32; off > 0; off >>= 1) s += __shfl_down(s, off, 64);
    if ((t & 63) == 0) redf[t >> 6] = s;
    __syncthreads();
    if (t == 0)
      out[0] = (redf[0] + redf[1] + redf[2] + redf[3]) * (1.0f / 12288.0f);
  }
}

// ---------- atomic fallback (proven R0/R2 structure, self-contained) ----------
__global__ __launch_bounds__(256, 2) void ect_main_at(
    const float* __restrict__ pred, const int* __restrict__ tgt,
    float* __restrict__ gacc) {
  __shared__ float dirs[96];
  __shared__ float4 voxdw[216];
  __shared__ float4 voxcl[216];
  const int t = threadIdx.x;
  const int bx = blockIdx.x;
  const int d = t & 31;
  const int rg = t >> 5;
  const int cbase = bx * 216;

  if (t < 96) {
    uint32_t o0, o1;
    threefry_0_17(0u, (uint32_t)t, o0, o1);
    uint32_t bits = o0 ^ o1;
    float u = __uint_as_float((bits >> 9) | 0x3F800000u) - 1.0f;
    const float lo = -0.99999994f;
    float v = fmaf(u, 2.0f, lo);
    v = fmaxf(v, lo);
    dirs[t] = 1.41421356237f * erfinv_f32(v);
  }
  __syncthreads();
  if (t < 32) {
    float a = dirs[t], b = dirs[32 + t], c = dirs[64 + t];
    float n = fmaxf(sqrtf(a * a + b * b + c * c), 1e-12f);
    dirs[t] = a / n; dirs[32 + t] = b / n; dirs[64 + t] = c / n;
  }
  if (t < 216) {
    int p = cbase + t;
    int ix = p / 2304; int rem = p - ix * 2304;
    int iy = rem / 48; int iz = rem - iy * 48;
    const float delta = 2.0f / 47.0f;
    voxcl[t] = float4{(float)ix * delta - 1.0f, (float)iy * delta - 1.0f,
                      (float)iz * delta - 1.0f, 0.0f};
    float w[4];
#pragma unroll
    for (int b = 0; b < 2; b++) {
      const float* pb = pred + b * (3 * P_TOT) + p;
      float x0 = pb[0], x1 = pb[P_TOT], x2 = pb[2 * P_TOT];
      float m = fmaxf(x0, fmaxf(x1, x2));
      float e0 = __expf(x0 - m), e1 = __expf(x1 - m), e2 = __expf(x2 - m);
      float inv = 1.0f / (e0 + e1 + e2);
      int tg = tgt[b * P_TOT + p];
      w[b * 2 + 0] = e0 * inv - ((tg == 0) ? 1.0f : 0.0f);
      w[b * 2 + 1] = e1 * inv - ((tg == 1) ? 1.0f : 0.0f);
    }
    voxdw[t] = float4{w[0], w[1], w[2], w[3]};
  }
  __syncthreads();

  const float dir0 = dirs[d], dir1 = dirs[32 + d], dir2 = dirs[64 + d];
  const float radius = 1.1f * 1.7320508075688772f;
  const float step = (2.0f * radius) / 63.0f;
  float K[8];
#pragma unroll
  for (int j = 0; j < 8; j++) {
    float lin = fmaf((float)(rg * 8 + j), step, -radius);
    K[j] = __expf(-8.0f * lin);
  }
  float acc[8][4];
#pragma unroll
  for (int j = 0; j < 8; j++)
#pragma unroll
    for (int bc = 0; bc < 4; bc++) acc[j][bc] = 0.0f;

#pragma unroll 4
  for (int v = 0; v < 216; v++) {
    float4 c = voxcl[v];
    float4 w = voxdw[v];
    float nh = fmaf(c.z, dir2, fmaf(c.y, dir1, c.x * dir0));
    float E = __expf(8.0f * nh);
    float z[8];
#pragma unroll
    for (int j = 0; j < 8; j++) z[j] = fmaf(E, K[j], 1.0f);
#pragma unroll
    for (int h = 0; h < 4; h++) {
      float pz = z[2 * h] * z[2 * h + 1];
      float rr = __builtin_amdgcn_rcpf(pz);
      float s0 = z[2 * h + 1] * rr;
      float s1 = z[2 * h] * rr;
      acc[2 * h][0] = fmaf(w.x, s0, acc[2 * h][0]);
      acc[2 * h][1] = fmaf(w.y, s0, acc[2 * h][1]);
      acc[2 * h][2] = fmaf(w.z, s0, acc[2 * h][2]);
      acc[2 * h][3] = fmaf(w.w, s0, acc[2 * h][3]);
      acc[2 * h + 1][0] = fmaf(w.x, s1, acc[2 * h + 1][0]);
      acc[2 * h + 1][1] = fmaf(w.y, s1, acc[2 * h + 1][1]);
      acc[2 * h + 1][2] = fmaf(w.z, s1, acc[2 * h + 1][2]);
      acc[2 * h + 1][3] = fmaf(w.w, s1, acc[2 * h + 1][3]);
    }
  }

  float* grep = gacc + (size_t)(bx & (NREP - 1)) * 8192;
#pragma unroll
  for (int j = 0; j < 8; j++) {
    int base = ((rg * 8 + j) * 32 + d) * 4;
    atomicAdd(&grep[base + 0], acc[j][0]);
    atomicAdd(&grep[base + 1], acc[j][1]);
    atomicAdd(&grep[base + 2], acc[j][2]);
    atomicAdd(&grep[base + 3], acc[j][3]);
  }
}

__global__ __launch_bounds__(256) void ect_fin(
    const float* __restrict__ gacc, float* __restrict__ out) {
  __shared__ float red[4];
  int t = threadIdx.x;
  float s = 0.0f;
  for (int i = t; i < 2048; i += 256) {
    float a0 = 0.f, a1 = 0.f, a2 = 0.f, a3 = 0.f;
#pragma unroll
    for (int rep = 0; rep < NREP; rep++) {
      const float4 g = *(const float4*)(gacc + (size_t)rep * 8192 + i * 4);
      a0 += g.x; a1 += g.y; a2 += g.z; a3 += g.w;
    }
    s += a0 * a0 + a1 * a1 + (a0 + a1) * (a0 + a1)
       + a2 * a2 + a3 * a3 + (a2 + a3) * (a2 + a3);
  }
#pragma unroll
  for (int off = 32; off > 0; off >>= 1) s += __shfl_down(s, off, 64);
  if ((t & 63) == 0) red[t >> 6] = s;
  __syncthreads();
  if (t == 0) out[0] = (red[0] + red[1] + red[2] + red[3]) * (1.0f / 12288.0f);
}

extern "C" void kernel_launch(void* const* d_in, const int* in_sizes, int n_in,
                              void* d_out, int out_size, void* d_ws, size_t ws_size,
                              hipStream_t stream) {
  const float* pred = (const float*)d_in[0];
  const int* tgt = (const int*)d_in[1];
  float* ws = (float*)d_ws;
  float* out = (float*)d_out;

  // layout (floats): part | gacc2(8192+64) | voxc(P*4) | voxw(P*4)
  const size_t vox_fl = (size_t)P_TOT * 4;
  const size_t needA = ((size_t)1024 * 8192 + 8256 + 2 * vox_fl) * sizeof(float);
  const size_t needB = ((size_t)512 * 8192 + 8256 + 2 * vox_fl) * sizeof(float);

  if (ws_size >= needA) {
    float* part = ws;                                    // [1024][8192]
    float* gacc2 = ws + (size_t)1024 * 8192;
    float4* voxc = (float4*)(gacc2 + 8256);
    float4* voxw = voxc + P_TOT;
    hipMemsetAsync(gacc2, 0, (8192 + 64) * sizeof(float), stream);
    hipLaunchKernelGGL(ect_pre, dim3(432), dim3(256), 0, stream,
                       pred, tgt, voxc, voxw);
    hipLaunchKernelGGL(ect_main_sm<108>, dim3(1024), dim3(256), 0, stream,
                       voxc, voxw, part);
    hipLaunchKernelGGL(ect_red, dim3(256), dim3(256), 0, stream,
                       part, gacc2, out, 256);
  } else if (ws_size >= needB) {
    float* part = ws;                                    // [512][8192]
    float* gacc2 = ws + (size_t)512 * 8192;
    float4* voxc = (float4*)(gacc2 + 8256);
    float4* voxw = voxc + P_TOT;
    hipMemsetAsync(gacc2, 0, (8192 + 64) * sizeof(float), stream);
    hipLaunchKernelGGL(ect_pre, dim3(432), dim3(256), 0, stream,
                       pred, tgt, voxc, voxw);
    hipLaunchKernelGGL(ect_main_sm<216>, dim3(512), dim3(256), 0, stream,
                       voxc, voxw, part);
    hipLaunchKernelGGL(ect_red, dim3(128), dim3(256), 0, stream,
                       part, gacc2, out, 128);
  } else {
    float* gacc = ws;                                    // 4*8192 floats
    hipMemsetAsync(gacc, 0, (size_t)NREP * 8192 * sizeof(float), stream);
    hipLaunchKernelGGL(ect_main_at, dim3(512), dim3(256), 0, stream,
                       pred, tgt, gacc);
    hipLaunchKernelGGL(ect_fin, dim3(1), dim3(256), 0, stream, gacc, out);
  }
}

// Round 7
// 113.437 us; speedup vs baseline: 1.0569x; 1.0496x over previous
//
#include <hip/hip_runtime.h>
#include <cstdint>

// ECT loss, exact elementwise formulation (absmax 0.0 preserved).
// A[bc][r][d] = sum_p dw[b,p,c] * sigmoid(8*(lin_r - <x_p, v_d>)), c in {0,1};
// c2 = -(c0+c1); loss = mean over 12288.
//
// R7: software-pipeline the inner loop (source-level), R4 structure otherwise.
//  * R6 lesson: LDS pipe exonerated (zero in-loop LDS -> 57us, no change);
//    separate pre-kernel costs a ~4us launch gap. Reverted both.
//  * Diagnosis: ~40% issue-idle at constant 33us VALU-busy across 5 rounds =
//    loop-boundary load-latency exposure (compiler doesn't modulo-schedule
//    across unroll groups) + trans chain. Fixes, both bit-exact:
//    - register rotation: voxel v+1's c/w loaded at top of body, used next
//      iteration -> ds_read issued ~112cy ahead of use at every boundary.
//    - phase-ordered body: all z -> all rcp (trans latencies overlap) ->
//      all s -> 32-fma burst (pure issue, no stalls).
// Fallback chain by ws_size: 1024-store -> 512-store -> atomic (proven R0).

#define P_TOT 110592
#define NREP 4  // atomic fallback only

__device__ __forceinline__ uint32_t rotl32(uint32_t x, int d) {
  return (x << d) | (x >> (32 - d));
}

// threefry2x32, key = (0,17) — bit-exact vs jax (verified)
__device__ __forceinline__ void threefry_0_17(uint32_t x0, uint32_t x1,
                                              uint32_t& o0, uint32_t& o1) {
  const uint32_t ks0 = 0u, ks1 = 17u, ks2 = 0x1BD11BDAu ^ 0u ^ 17u;
  x0 += ks0; x1 += ks1;
#define R4(a,b,c,dd) \
  x0 += x1; x1 = rotl32(x1,(a)); x1 ^= x0; \
  x0 += x1; x1 = rotl32(x1,(b)); x1 ^= x0; \
  x0 += x1; x1 = rotl32(x1,(c)); x1 ^= x0; \
  x0 += x1; x1 = rotl32(x1,(dd)); x1 ^= x0;
  R4(13,15,26,6)   x0 += ks1; x1 += ks2 + 1u;
  R4(17,29,16,24)  x0 += ks2; x1 += ks0 + 2u;
  R4(13,15,26,6)   x0 += ks0; x1 += ks1 + 3u;
  R4(17,29,16,24)  x0 += ks1; x1 += ks2 + 4u;
  R4(13,15,26,6)   x0 += ks2; x1 += ks0 + 5u;
#undef R4
  o0 = x0; o1 = x1;
}

// XLA ErfInv32 — bit-exact vs jax (verified)
__device__ __forceinline__ float erfinv_f32(float x) {
  float w = -log1pf(-x * x);
  float p;
  if (w < 5.0f) {
    w = w - 2.5f;
    p = 2.81022636e-08f;
    p = fmaf(p, w, 3.43273939e-07f);
    p = fmaf(p, w, -3.5233877e-06f);
    p = fmaf(p, w, -4.39150654e-06f);
    p = fmaf(p, w, 0.00021858087f);
    p = fmaf(p, w, -0.00125372503f);
    p = fmaf(p, w, -0.00417768164f);
    p = fmaf(p, w, 0.246640727f);
    p = fmaf(p, w, 1.50140941f);
  } else {
    w = sqrtf(w) - 3.0f;
    p = -0.000200214257f;
    p = fmaf(p, w, 0.000100950558f);
    p = fmaf(p, w, 0.00134934322f);
    p = fmaf(p, w, 0.000337081863f);
    p = fmaf(p, w, 0.00573950773f);
    p = fmaf(p, w, -0.0076224613f);
    p = fmaf(p, w, 0.00943887047f);
    p = fmaf(p, w, 1.00167406f);
    p = fmaf(p, w, 2.83297682f);
  }
  return p * x;
}

// Phase-ordered voxel body: identical ops/inputs as R3/R4, reordered only.
#define ECT_BODY(cc_, ww_)                                                 \
  {                                                                        \
    float nh = fmaf((cc_).z, dir2, fmaf((cc_).y, dir1, (cc_).x * dir0));   \
    float E = __expf(8.0f * nh);          /* <= e^13.9, no overflow */     \
    float z[8];                                                            \
    _Pragma("unroll")                                                      \
    for (int j = 0; j < 8; j++) z[j] = fmaf(E, K[j], 1.0f); /*1..4.4e12*/  \
    float rr[4];                          /* paired rcp: <=2e25, no ovf */ \
    _Pragma("unroll")                                                      \
    for (int h = 0; h < 4; h++)                                            \
      rr[h] = __builtin_amdgcn_rcpf(z[2 * h] * z[2 * h + 1]);              \
    float s[8];                                                            \
    _Pragma("unroll")                                                      \
    for (int h = 0; h < 4; h++) {                                          \
      s[2 * h] = z[2 * h + 1] * rr[h];                                     \
      s[2 * h + 1] = z[2 * h] * rr[h];                                     \
    }                                                                      \
    _Pragma("unroll")                                                      \
    for (int j = 0; j < 8; j++) {                                          \
      acc[j][0] = fmaf((ww_).x, s[j], acc[j][0]);                          \
      acc[j][1] = fmaf((ww_).y, s[j], acc[j][1]);                          \
      acc[j][2] = fmaf((ww_).z, s[j], acc[j][2]);                          \
      acc[j][3] = fmaf((ww_).w, s[j], acc[j][3]);                          \
    }                                                                      \
  }

// ---------- shared compute (prologue + pipelined main loop) ----------
template <int VOXN>
__device__ __forceinline__ void ect_block_compute(
    const float* __restrict__ pred, const int* __restrict__ tgt,
    float* dirs, float4* voxdw, float4* voxc,
    int t, int bx, float acc[8][4]) {
  const int d = t & 31;
  const int rg = t >> 5;
  const int cbase = bx * VOXN;

  if (t < 96) {
    uint32_t o0, o1;
    threefry_0_17(0u, (uint32_t)t, o0, o1);
    uint32_t bits = o0 ^ o1;
    float u = __uint_as_float((bits >> 9) | 0x3F800000u) - 1.0f;
    const float lo = -0.99999994f;
    float v = fmaf(u, 2.0f, lo);
    v = fmaxf(v, lo);
    dirs[t] = 1.41421356237f * erfinv_f32(v);
  }
  __syncthreads();
  if (t < 32) {
    float a = dirs[t], b = dirs[32 + t], c = dirs[64 + t];
    float n = fmaxf(sqrtf(a * a + b * b + c * c), 1e-12f);
    dirs[t] = a / n; dirs[32 + t] = b / n; dirs[64 + t] = c / n;
  }
  if (t < VOXN) {
    int p = cbase + t;
    int ix = p / 2304; int rem = p - ix * 2304;
    int iy = rem / 48; int iz = rem - iy * 48;
    const float delta = 2.0f / 47.0f;
    voxc[t] = float4{(float)ix * delta - 1.0f, (float)iy * delta - 1.0f,
                     (float)iz * delta - 1.0f, 0.0f};
    float w[4];
#pragma unroll
    for (int b = 0; b < 2; b++) {
      const float* pb = pred + b * (3 * P_TOT) + p;
      float x0 = pb[0], x1 = pb[P_TOT], x2 = pb[2 * P_TOT];
      float m = fmaxf(x0, fmaxf(x1, x2));
      float e0 = __expf(x0 - m), e1 = __expf(x1 - m), e2 = __expf(x2 - m);
      float inv = 1.0f / (e0 + e1 + e2);
      int tg = tgt[b * P_TOT + p];
      w[b * 2 + 0] = e0 * inv - ((tg == 0) ? 1.0f : 0.0f);
      w[b * 2 + 1] = e1 * inv - ((tg == 1) ? 1.0f : 0.0f);
    }
    voxdw[t] = float4{w[0], w[1], w[2], w[3]};
  }
  __syncthreads();

  const float dir0 = dirs[d], dir1 = dirs[32 + d], dir2 = dirs[64 + d];
  const float radius = 1.1f * 1.7320508075688772f;
  const float step = (2.0f * radius) / 63.0f;
  float K[8];
#pragma unroll
  for (int j = 0; j < 8; j++) {
    float lin = fmaf((float)(rg * 8 + j), step, -radius);
    K[j] = __expf(-8.0f * lin);
  }
#pragma unroll
  for (int j = 0; j < 8; j++)
#pragma unroll
    for (int bc = 0; bc < 4; bc++) acc[j][bc] = 0.0f;

  // main loop: register-rotation prefetch (loads issued one body ahead)
  float4 c_cur = voxc[0];
  float4 w_cur = voxdw[0];
#pragma unroll 4
  for (int v = 0; v < VOXN - 1; v++) {
    float4 c_nxt = voxc[v + 1];
    float4 w_nxt = voxdw[v + 1];
    ECT_BODY(c_cur, w_cur);
    c_cur = c_nxt;
    w_cur = w_nxt;
  }
  ECT_BODY(c_cur, w_cur);   // peeled last voxel
}

// ---------- store path ----------
template <int VOXN>
__global__ __launch_bounds__(256, 2) void ect_main_st(
    const float* __restrict__ pred, const int* __restrict__ tgt,
    float* __restrict__ part) {
  __shared__ float dirs[96];
  __shared__ float4 voxdw[VOXN];
  __shared__ float4 voxc[VOXN];
  const int t = threadIdx.x;
  const int bx = blockIdx.x;
  const int d = t & 31;
  const int rg = t >> 5;
  float acc[8][4];
  ect_block_compute<VOXN>(pred, tgt, dirs, voxdw, voxc, t, bx, acc);

  // pure coalesced stores: part[bx][(r*32+d)*4 + bc]
  float4* prt = (float4*)part + (size_t)bx * 2048;
#pragma unroll
  for (int j = 0; j < 8; j++) {
    prt[(rg * 8 + j) * 32 + d] =
        float4{acc[j][0], acc[j][1], acc[j][2], acc[j][3]};
  }
}

__global__ __launch_bounds__(256) void ect_red(
    const float* __restrict__ part, float* __restrict__ gacc2,
    float* __restrict__ out, int ngrid) {
  __shared__ float redf[4];
  __shared__ int islast;
  const int t = threadIdx.x;
  const int rc = blockIdx.x >> 3;       // slice chunk (32 slices each)
  const int cc = blockIdx.x & 7;        // column chunk (256 float4)
  const int c4 = cc * 256 + t;          // float4 column in [0, 2048)
  const float4* p4 = (const float4*)part;

  float a0 = 0.f, a1 = 0.f, a2 = 0.f, a3 = 0.f;
#pragma unroll 8
  for (int r = rc * 32; r < rc * 32 + 32; ++r) {
    float4 v = p4[(size_t)r * 2048 + c4];   // 1KB-coalesced per wave per r
    a0 += v.x; a1 += v.y; a2 += v.z; a3 += v.w;
  }
  atomicAdd(&gacc2[c4 * 4 + 0], a0);
  atomicAdd(&gacc2[c4 * 4 + 1], a1);
  atomicAdd(&gacc2[c4 * 4 + 2], a2);
  atomicAdd(&gacc2[c4 * 4 + 3], a3);

  __syncthreads();                       // drains vmcnt(0) per wave
  unsigned int* cnt = (unsigned int*)(gacc2 + 8192);
  if (t == 0) {
    unsigned int old = __hip_atomic_fetch_add(cnt, 1u, __ATOMIC_RELAXED,
                                              __HIP_MEMORY_SCOPE_AGENT);
    islast = (old == (unsigned int)(ngrid - 1)) ? 1 : 0;
  }
  __syncthreads();
  if (islast) {
    float s = 0.0f;
    for (int i = t; i < 2048; i += 256) {  // i = r*32 + d
      const unsigned long long* p64 =
          (const unsigned long long*)(gacc2 + i * 4);
      unsigned long long q0 = __hip_atomic_load(p64, __ATOMIC_RELAXED,
                                                __HIP_MEMORY_SCOPE_AGENT);
      unsigned long long q1 = __hip_atomic_load(p64 + 1, __ATOMIC_RELAXED,
                                                __HIP_MEMORY_SCOPE_AGENT);
      float b0 = __uint_as_float((unsigned int)q0);
      float b1 = __uint_as_float((unsigned int)(q0 >> 32));
      float b2 = __uint_as_float((unsigned int)q1);
      float b3 = __uint_as_float((unsigned int)(q1 >> 32));
      s += b0 * b0 + b1 * b1 + (b0 + b1) * (b0 + b1)
         + b2 * b2 + b3 * b3 + (b2 + b3) * (b2 + b3);
    }
#pragma unroll
    for (int off = 32; off > 0; off >>= 1) s += __shfl_down(s, off, 64);
    if ((t & 63) == 0) redf[t >> 6] = s;
    __syncthreads();
    if (t == 0)
      out[0] = (redf[0] + redf[1] + redf[2] + redf[3]) * (1.0f / 12288.0f);
  }
}

// ---------- atomic fallback (proven structure) ----------
__global__ __launch_bounds__(256, 2) void ect_main_at(
    const float* __restrict__ pred, const int* __restrict__ tgt,
    float* __restrict__ gacc) {
  __shared__ float dirs[96];
  __shared__ float4 voxdw[216];
  __shared__ float4 voxc[216];
  const int t = threadIdx.x;
  const int bx = blockIdx.x;
  const int d = t & 31;
  const int rg = t >> 5;
  float acc[8][4];
  ect_block_compute<216>(pred, tgt, dirs, voxdw, voxc, t, bx, acc);

  float* grep = gacc + (size_t)(bx & (NREP - 1)) * 8192;
#pragma unroll
  for (int j = 0; j < 8; j++) {
    int base = ((rg * 8 + j) * 32 + d) * 4;
    atomicAdd(&grep[base + 0], acc[j][0]);
    atomicAdd(&grep[base + 1], acc[j][1]);
    atomicAdd(&grep[base + 2], acc[j][2]);
    atomicAdd(&grep[base + 3], acc[j][3]);
  }
}

__global__ __launch_bounds__(256) void ect_fin(
    const float* __restrict__ gacc, float* __restrict__ out) {
  __shared__ float red[4];
  int t = threadIdx.x;
  float s = 0.0f;
  for (int i = t; i < 2048; i += 256) {
    float a0 = 0.f, a1 = 0.f, a2 = 0.f, a3 = 0.f;
#pragma unroll
    for (int rep = 0; rep < NREP; rep++) {
      const float4 g = *(const float4*)(gacc + (size_t)rep * 8192 + i * 4);
      a0 += g.x; a1 += g.y; a2 += g.z; a3 += g.w;
    }
    s += a0 * a0 + a1 * a1 + (a0 + a1) * (a0 + a1)
       + a2 * a2 + a3 * a3 + (a2 + a3) * (a2 + a3);
  }
#pragma unroll
  for (int off = 32; off > 0; off >>= 1) s += __shfl_down(s, off, 64);
  if ((t & 63) == 0) red[t >> 6] = s;
  __syncthreads();
  if (t == 0) out[0] = (red[0] + red[1] + red[2] + red[3]) * (1.0f / 12288.0f);
}

extern "C" void kernel_launch(void* const* d_in, const int* in_sizes, int n_in,
                              void* d_out, int out_size, void* d_ws, size_t ws_size,
                              hipStream_t stream) {
  const float* pred = (const float*)d_in[0];
  const int* tgt = (const int*)d_in[1];
  float* ws = (float*)d_ws;
  float* out = (float*)d_out;

  const size_t need1024 = ((size_t)1024 * 8192 + 8192 + 64) * sizeof(float);
  const size_t need512 = ((size_t)512 * 8192 + 8192 + 64) * sizeof(float);

  if (ws_size >= need1024) {
    // 1024 blocks x 108 voxels (4 blocks/CU co-resident)
    float* part = ws;                                   // [1024][8192]
    float* gacc2 = ws + (size_t)1024 * 8192;
    hipMemsetAsync(gacc2, 0, (8192 + 64) * sizeof(float), stream);
    hipLaunchKernelGGL(ect_main_st<108>, dim3(1024), dim3(256), 0, stream,
                       pred, tgt, part);
    hipLaunchKernelGGL(ect_red, dim3(256), dim3(256), 0, stream,
                       part, gacc2, out, 256);
  } else if (ws_size >= need512) {
    float* part = ws;                                   // [512][8192]
    float* gacc2 = ws + (size_t)512 * 8192;
    hipMemsetAsync(gacc2, 0, (8192 + 64) * sizeof(float), stream);
    hipLaunchKernelGGL(ect_main_st<216>, dim3(512), dim3(256), 0, stream,
                       pred, tgt, part);
    hipLaunchKernelGGL(ect_red, dim3(128), dim3(256), 0, stream,
                       part, gacc2, out, 128);
  } else {
    float* gacc = ws;                                   // 4*8192 floats
    hipMemsetAsync(gacc, 0, (size_t)NREP * 8192 * sizeof(float), stream);
    hipLaunchKernelGGL(ect_main_at, dim3(512), dim3(256), 0, stream,
                       pred, tgt, gacc);
    hipLaunchKernelGGL(ect_fin, dim3(1), dim3(256), 0, stream, gacc, out);
  }
}

// Round 8
// 108.912 us; speedup vs baseline: 1.1008x; 1.0415x over previous
//
#include <hip/hip_runtime.h>
#include <cstdint>

// ECT loss, exact elementwise formulation (absmax 0.0 preserved).
// A[bc][r][d] = sum_p dw[b,p,c] * sigmoid(8*(lin_r - <x_p, v_d>)), c in {0,1};
// c2 = -(c0+c1); loss = mean over 12288.
//
// R8: remove redundant issued work (the SIMD issue port is ~80% saturated;
// occupancy/LDS/pipelining all exonerated in R4/R6/R7).
//  * Etab[v][d] = exp(8*<x_v, dir_d>) computed ONCE per (voxel,dir) into LDS
//    instead of once per (voxel,dir,rg-group) — kills 3 fma + 2 mul + 1 v_exp
//    (~11% of issue cycles) per voxel-thread, replaced by a conflict-free
//    broadcast ds_read_b32. Bit-exact: identical fmaf/exp expression.
//    (R1 tried this but confounded with 512-thr split + per-wave threadfence;
//    this is the isolated test on the proven R4 structure.)
//  * memset dispatch folded into ect_main (blocks 0..8 zero gacc2+ticket);
//    graph is now 2 nodes — saves the ~4-5us per-dispatch gap.
//  * R7's rotation prefetch reverted (cost ~3%: extra movs, no stall win).
// Fallback chain by ws_size: 1024-store -> 512-store -> atomic (proven R0).

#define P_TOT 110592
#define NREP 4  // atomic fallback only

__device__ __forceinline__ uint32_t rotl32(uint32_t x, int d) {
  return (x << d) | (x >> (32 - d));
}

// threefry2x32, key = (0,17) — bit-exact vs jax (verified)
__device__ __forceinline__ void threefry_0_17(uint32_t x0, uint32_t x1,
                                              uint32_t& o0, uint32_t& o1) {
  const uint32_t ks0 = 0u, ks1 = 17u, ks2 = 0x1BD11BDAu ^ 0u ^ 17u;
  x0 += ks0; x1 += ks1;
#define R4(a,b,c,dd) \
  x0 += x1; x1 = rotl32(x1,(a)); x1 ^= x0; \
  x0 += x1; x1 = rotl32(x1,(b)); x1 ^= x0; \
  x0 += x1; x1 = rotl32(x1,(c)); x1 ^= x0; \
  x0 += x1; x1 = rotl32(x1,(dd)); x1 ^= x0;
  R4(13,15,26,6)   x0 += ks1; x1 += ks2 + 1u;
  R4(17,29,16,24)  x0 += ks2; x1 += ks0 + 2u;
  R4(13,15,26,6)   x0 += ks0; x1 += ks1 + 3u;
  R4(17,29,16,24)  x0 += ks1; x1 += ks2 + 4u;
  R4(13,15,26,6)   x0 += ks2; x1 += ks0 + 5u;
#undef R4
  o0 = x0; o1 = x1;
}

// XLA ErfInv32 — bit-exact vs jax (verified)
__device__ __forceinline__ float erfinv_f32(float x) {
  float w = -log1pf(-x * x);
  float p;
  if (w < 5.0f) {
    w = w - 2.5f;
    p = 2.81022636e-08f;
    p = fmaf(p, w, 3.43273939e-07f);
    p = fmaf(p, w, -3.5233877e-06f);
    p = fmaf(p, w, -4.39150654e-06f);
    p = fmaf(p, w, 0.00021858087f);
    p = fmaf(p, w, -0.00125372503f);
    p = fmaf(p, w, -0.00417768164f);
    p = fmaf(p, w, 0.246640727f);
    p = fmaf(p, w, 1.50140941f);
  } else {
    w = sqrtf(w) - 3.0f;
    p = -0.000200214257f;
    p = fmaf(p, w, 0.000100950558f);
    p = fmaf(p, w, 0.00134934322f);
    p = fmaf(p, w, 0.000337081863f);
    p = fmaf(p, w, 0.00573950773f);
    p = fmaf(p, w, -0.0076224613f);
    p = fmaf(p, w, 0.00943887047f);
    p = fmaf(p, w, 1.00167406f);
    p = fmaf(p, w, 2.83297682f);
  }
  return p * x;
}

// ---------- shared compute: prologue + Etab + main loop ----------
template <int VOXN>
__device__ __forceinline__ void ect_block_compute(
    const float* __restrict__ pred, const int* __restrict__ tgt,
    float* dirs, float4* voxdw, float* Etab,
    int t, int bx, float acc[8][4]) {
  const int d = t & 31;
  const int rg = t >> 5;
  const int cbase = bx * VOXN;

  if (t < 96) {
    uint32_t o0, o1;
    threefry_0_17(0u, (uint32_t)t, o0, o1);
    uint32_t bits = o0 ^ o1;
    float u = __uint_as_float((bits >> 9) | 0x3F800000u) - 1.0f;
    const float lo = -0.99999994f;
    float v = fmaf(u, 2.0f, lo);
    v = fmaxf(v, lo);
    dirs[t] = 1.41421356237f * erfinv_f32(v);
  }
  __syncthreads();
  if (t < 32) {
    float a = dirs[t], b = dirs[32 + t], c = dirs[64 + t];
    float n = fmaxf(sqrtf(a * a + b * b + c * c), 1e-12f);
    dirs[t] = a / n; dirs[32 + t] = b / n; dirs[64 + t] = c / n;
  }
  if (t < VOXN) {   // voxdw: independent of dirs, overlaps normalize
    int p = cbase + t;
    float w[4];
#pragma unroll
    for (int b = 0; b < 2; b++) {
      const float* pb = pred + b * (3 * P_TOT) + p;
      float x0 = pb[0], x1 = pb[P_TOT], x2 = pb[2 * P_TOT];
      float m = fmaxf(x0, fmaxf(x1, x2));
      float e0 = __expf(x0 - m), e1 = __expf(x1 - m), e2 = __expf(x2 - m);
      float inv = 1.0f / (e0 + e1 + e2);
      int tg = tgt[b * P_TOT + p];
      w[b * 2 + 0] = e0 * inv - ((tg == 0) ? 1.0f : 0.0f);
      w[b * 2 + 1] = e1 * inv - ((tg == 1) ? 1.0f : 0.0f);
    }
    voxdw[t] = float4{w[0], w[1], w[2], w[3]};
  }
  __syncthreads();

  // Etab fill: needs normalized dirs. Identical nh/exp expression as the old
  // in-loop computation -> bit-exact. ~VOXN*32/256 iters per thread.
  const float delta = 2.0f / 47.0f;
  for (int i = t; i < VOXN * 32; i += 256) {
    int v = i >> 5, dd = i & 31;
    int p = cbase + v;
    int ix = p / 2304; int rem = p - ix * 2304;
    int iy = rem / 48; int iz = rem - iy * 48;
    float cx = (float)ix * delta - 1.0f;
    float cy = (float)iy * delta - 1.0f;
    float cz = (float)iz * delta - 1.0f;
    float nh = fmaf(cz, dirs[64 + dd], fmaf(cy, dirs[32 + dd], cx * dirs[dd]));
    Etab[i] = __expf(8.0f * nh);        // <= e^13.9, no overflow
  }
  __syncthreads();

  const float radius = 1.1f * 1.7320508075688772f;
  const float step = (2.0f * radius) / 63.0f;
  float K[8];
#pragma unroll
  for (int j = 0; j < 8; j++) {
    float lin = fmaf((float)(rg * 8 + j), step, -radius);
    K[j] = __expf(-8.0f * lin);
  }
#pragma unroll
  for (int j = 0; j < 8; j++)
#pragma unroll
    for (int bc = 0; bc < 4; bc++) acc[j][bc] = 0.0f;

  // main loop: E via broadcast ds_read_b32 (lanes 0-31 consecutive dwords,
  // lanes 32-63 same addresses -> 2-way same-address broadcast, free)
#pragma unroll 4
  for (int v = 0; v < VOXN; v++) {
    float4 w = voxdw[v];
    float E = Etab[(v << 5) + d];
    float z[8];
#pragma unroll
    for (int j = 0; j < 8; j++) z[j] = fmaf(E, K[j], 1.0f);  // 1..4.4e12
#pragma unroll
    for (int h = 0; h < 4; h++) {
      // paired reciprocal: product <= 2e25, no overflow
      float pz = z[2 * h] * z[2 * h + 1];
      float rr = __builtin_amdgcn_rcpf(pz);
      float s0 = z[2 * h + 1] * rr;           // sigmoid for r = rg*8+2h
      float s1 = z[2 * h] * rr;               // sigmoid for r = rg*8+2h+1
      acc[2 * h][0] = fmaf(w.x, s0, acc[2 * h][0]);
      acc[2 * h][1] = fmaf(w.y, s0, acc[2 * h][1]);
      acc[2 * h][2] = fmaf(w.z, s0, acc[2 * h][2]);
      acc[2 * h][3] = fmaf(w.w, s0, acc[2 * h][3]);
      acc[2 * h + 1][0] = fmaf(w.x, s1, acc[2 * h + 1][0]);
      acc[2 * h + 1][1] = fmaf(w.y, s1, acc[2 * h + 1][1]);
      acc[2 * h + 1][2] = fmaf(w.z, s1, acc[2 * h + 1][2]);
      acc[2 * h + 1][3] = fmaf(w.w, s1, acc[2 * h + 1][3]);
    }
  }
}

// ---------- store path ----------
template <int VOXN>
__global__ __launch_bounds__(256, 2) void ect_main_st(
    const float* __restrict__ pred, const int* __restrict__ tgt,
    float* __restrict__ part, float* __restrict__ gacc2) {
  __shared__ float dirs[96];
  __shared__ float4 voxdw[VOXN];
  __shared__ float Etab[VOXN * 32];
  const int t = threadIdx.x;
  const int bx = blockIdx.x;
  const int d = t & 31;
  const int rg = t >> 5;

  // folded memset: blocks 0..7 zero gacc2 (8192 floats), block 8 the ticket.
  // Visible to ect_red via stream-order kernel boundary.
  if (bx < 8) {
    ((float4*)gacc2)[bx * 256 + t] = float4{0.0f, 0.0f, 0.0f, 0.0f};
  }
  if (bx == 8 && t == 0) *(unsigned int*)(gacc2 + 8192) = 0u;

  float acc[8][4];
  ect_block_compute<VOXN>(pred, tgt, dirs, voxdw, Etab, t, bx, acc);

  // pure coalesced stores: part[bx][(r*32+d)*4 + bc]
  float4* prt = (float4*)part + (size_t)bx * 2048;
#pragma unroll
  for (int j = 0; j < 8; j++) {
    prt[(rg * 8 + j) * 32 + d] =
        float4{acc[j][0], acc[j][1], acc[j][2], acc[j][3]};
  }
}

__global__ __launch_bounds__(256) void ect_red(
    const float* __restrict__ part, float* __restrict__ gacc2,
    float* __restrict__ out, int ngrid) {
  __shared__ float redf[4];
  __shared__ int islast;
  const int t = threadIdx.x;
  const int rc = blockIdx.x >> 3;       // slice chunk (32 slices each)
  const int cc = blockIdx.x & 7;        // column chunk (256 float4)
  const int c4 = cc * 256 + t;          // float4 column in [0, 2048)
  const float4* p4 = (const float4*)part;

  float a0 = 0.f, a1 = 0.f, a2 = 0.f, a3 = 0.f;
#pragma unroll 8
  for (int r = rc * 32; r < rc * 32 + 32; ++r) {
    float4 v = p4[(size_t)r * 2048 + c4];   // 1KB-coalesced per wave per r
    a0 += v.x; a1 += v.y; a2 += v.z; a3 += v.w;
  }
  atomicAdd(&gacc2[c4 * 4 + 0], a0);
  atomicAdd(&gacc2[c4 * 4 + 1], a1);
  atomicAdd(&gacc2[c4 * 4 + 2], a2);
  atomicAdd(&gacc2[c4 * 4 + 3], a3);

  __syncthreads();                       // drains vmcnt(0) per wave
  unsigned int* cnt = (unsigned int*)(gacc2 + 8192);
  if (t == 0) {
    unsigned int old = __hip_atomic_fetch_add(cnt, 1u, __ATOMIC_RELAXED,
                                              __HIP_MEMORY_SCOPE_AGENT);
    islast = (old == (unsigned int)(ngrid - 1)) ? 1 : 0;
  }
  __syncthreads();
  if (islast) {
    float s = 0.0f;
    for (int i = t; i < 2048; i += 256) {  // i = r*32 + d
      const unsigned long long* p64 =
          (const unsigned long long*)(gacc2 + i * 4);
      unsigned long long q0 = __hip_atomic_load(p64, __ATOMIC_RELAXED,
                                                __HIP_MEMORY_SCOPE_AGENT);
      unsigned long long q1 = __hip_atomic_load(p64 + 1, __ATOMIC_RELAXED,
                                                __HIP_MEMORY_SCOPE_AGENT);
      float b0 = __uint_as_float((unsigned int)q0);
      float b1 = __uint_as_float((unsigned int)(q0 >> 32));
      float b2 = __uint_as_float((unsigned int)q1);
      float b3 = __uint_as_float((unsigned int)(q1 >> 32));
      s += b0 * b0 + b1 * b1 + (b0 + b1) * (b0 + b1)
         + b2 * b2 + b3 * b3 + (b2 + b3) * (b2 + b3);
    }
#pragma unroll
    for (int off = 32; off > 0; off >>= 1) s += __shfl_down(s, off, 64);
    if ((t & 63) == 0) redf[t >> 6] = s;
    __syncthreads();
    if (t == 0)
      out[0] = (redf[0] + redf[1] + redf[2] + redf[3]) * (1.0f / 12288.0f);
  }
}

// ---------- atomic fallback (proven structure, Etab-based compute) ----------
__global__ __launch_bounds__(256, 2) void ect_main_at(
    const float* __restrict__ pred, const int* __restrict__ tgt,
    float* __restrict__ gacc) {
  __shared__ float dirs[96];
  __shared__ float4 voxdw[216];
  __shared__ float Etab[216 * 32];
  const int t = threadIdx.x;
  const int bx = blockIdx.x;
  const int d = t & 31;
  const int rg = t >> 5;
  float acc[8][4];
  ect_block_compute<216>(pred, tgt, dirs, voxdw, Etab, t, bx, acc);

  float* grep = gacc + (size_t)(bx & (NREP - 1)) * 8192;
#pragma unroll
  for (int j = 0; j < 8; j++) {
    int base = ((rg * 8 + j) * 32 + d) * 4;
    atomicAdd(&grep[base + 0], acc[j][0]);
    atomicAdd(&grep[base + 1], acc[j][1]);
    atomicAdd(&grep[base + 2], acc[j][2]);
    atomicAdd(&grep[base + 3], acc[j][3]);
  }
}

__global__ __launch_bounds__(256) void ect_fin(
    const float* __restrict__ gacc, float* __restrict__ out) {
  __shared__ float red[4];
  int t = threadIdx.x;
  float s = 0.0f;
  for (int i = t; i < 2048; i += 256) {
    float a0 = 0.f, a1 = 0.f, a2 = 0.f, a3 = 0.f;
#pragma unroll
    for (int rep = 0; rep < NREP; rep++) {
      const float4 g = *(const float4*)(gacc + (size_t)rep * 8192 + i * 4);
      a0 += g.x; a1 += g.y; a2 += g.z; a3 += g.w;
    }
    s += a0 * a0 + a1 * a1 + (a0 + a1) * (a0 + a1)
       + a2 * a2 + a3 * a3 + (a2 + a3) * (a2 + a3);
  }
#pragma unroll
  for (int off = 32; off > 0; off >>= 1) s += __shfl_down(s, off, 64);
  if ((t & 63) == 0) red[t >> 6] = s;
  __syncthreads();
  if (t == 0) out[0] = (red[0] + red[1] + red[2] + red[3]) * (1.0f / 12288.0f);
}

extern "C" void kernel_launch(void* const* d_in, const int* in_sizes, int n_in,
                              void* d_out, int out_size, void* d_ws, size_t ws_size,
                              hipStream_t stream) {
  const float* pred = (const float*)d_in[0];
  const int* tgt = (const int*)d_in[1];
  float* ws = (float*)d_ws;
  float* out = (float*)d_out;

  const size_t need1024 = ((size_t)1024 * 8192 + 8192 + 64) * sizeof(float);
  const size_t need512 = ((size_t)512 * 8192 + 8192 + 64) * sizeof(float);

  if (ws_size >= need1024) {
    // 1024 blocks x 108 voxels; no memset dispatch (folded into main)
    float* part = ws;                                   // [1024][8192]
    float* gacc2 = ws + (size_t)1024 * 8192;
    hipLaunchKernelGGL(ect_main_st<108>, dim3(1024), dim3(256), 0, stream,
                       pred, tgt, part, gacc2);
    hipLaunchKernelGGL(ect_red, dim3(256), dim3(256), 0, stream,
                       part, gacc2, out, 256);
  } else if (ws_size >= need512) {
    float* part = ws;                                   // [512][8192]
    float* gacc2 = ws + (size_t)512 * 8192;
    hipLaunchKernelGGL(ect_main_st<216>, dim3(512), dim3(256), 0, stream,
                       pred, tgt, part, gacc2);
    hipLaunchKernelGGL(ect_red, dim3(128), dim3(256), 0, stream,
                       part, gacc2, out, 128);
  } else {
    float* gacc = ws;                                   // 4*8192 floats
    hipMemsetAsync(gacc, 0, (size_t)NREP * 8192 * sizeof(float), stream);
    hipLaunchKernelGGL(ect_main_at, dim3(512), dim3(256), 0, stream,
                       pred, tgt, gacc);
    hipLaunchKernelGGL(ect_fin, dim3(1), dim3(256), 0, stream, gacc, out);
  }
}